// Round 6
// baseline (243.636 us; speedup 1.0000x reference)
//
#include <hip/hip_runtime.h>

// Izhikevich spiking neuron scan — two-pass split to unmix the DRAM streams.
//
// x: [T=512, N=65536] f32. out: [T, N] f32 spike train (0.0 / 1.0).
//
// Round-6 theory: five structurally different single-pass kernels all pin
// at 2.5-2.9 TB/s regardless of waves/CU (8..32) or guaranteed in-flight
// bytes (8..96 KB/CU) — a queuing equilibrium where the drain rate is set
// by DRAM efficiency for the pattern: ~4096 interleaved R/W cursors on
// 4 KB islands strided 256 KB => ~256 B per-channel runs + fine-grain R/W
// turnaround => ~40% efficiency (2.6/6.3). The m13 float4 copy (same 1:1
// R/W, dense sweeping window) does 6.3 TB/s; fillBuffer (pure write) does
// 6.7 TB/s on this very harness. Fix: the output is 1 bit/element, so:
//   k1 izi_pack:   scan + pack 32 fire-bits/neuron/chunk into uint32,
//                  stored INTO d_out at row tstart (bitcast) — 164 MB
//                  nearly-pure READ stream + 4 MB writes.
//   k2 izi_expand: per thread, read own packed word (L2/L3-hot; read-
//                  before-overwrite in-thread => race-free), NT-store 32
//                  rows of float2 — nearly-pure WRITE stream, fill-shaped.
// Same-stream launch order serializes k1 -> k2 (full inter-kernel
// visibility). Bit i of packed[c][n] = fire at t=c*32+i in both kernels.
//
// Recurrence (bit-identical to all verified prior versions, absmax 0.0):
//   v = (4v^2 + 5v + 1.4 - r + x_t) * DT   (DT = 1/512)
//   r = 0.02 * (0.2v - v) * DT             (uses NEW v)
//   fire = v >= 0.3 ; fire -> v = -0.065, r += 0.008 ; out_t = fire
//
// Time-split justification (verified absmax=0 five times): the map
// contracts prior state by ~(5/512)/step; 8 warmup steps shrink any
// init-state error below fp32 ulp.
//
// k1 is round-2's structure (best measured single-pass: ~74 us WITH
// per-step stores): float2, 16 chunks x 128 blocks = 2048 blocks
// (8 blocks/CU, 32 waves/CU), ping-pong buf[2][8] register pipeline with
// sched_barrier pinning — minus the 131 MB of per-step stores.

#define T_STEPS 512
#define N_NEUR  65536
#define N2      (N_NEUR / 2)     // 32768 float2 columns
#define DT      (1.0f / 512.0f)
#define NCHUNK  16
#define TCH     32               // timesteps per chunk == bits in a uint32
#define WARM    8
#define NP      8                // prefetch batch depth
#define NBLK    (TCH / NP)       // 4 tiles per chunk

typedef float v2f __attribute__((ext_vector_type(2)));
typedef unsigned int u32;
typedef u32 v2u __attribute__((ext_vector_type(2)));

__device__ __forceinline__ bool izi_step(float xt, float& v, float& r) {
    v = (4.0f * v * v + 5.0f * v + 1.4f - r + xt) * DT;
    r = 0.02f * (0.2f * v - v) * DT;
    const bool fire = v >= 0.3f;
    if (fire) { v = -0.065f; r += 0.008f; }
    return fire;
}

// ---------------- k1: scan + bit-pack (read-dominated) ----------------

__global__ __launch_bounds__(256, 8) void izi_pack(const v2f* __restrict__ x,
                                                   v2u* __restrict__ outp) {
    const int col = blockIdx.x * 256 + threadIdx.x;  // float2 column
    const int c = blockIdx.y;                        // time chunk 0..15
    const int tstart = c * TCH;

    float vx = -0.065f, vy = -0.065f;
    float rx = 0.0f,    ry = 0.0f;

    if (c > 0) {
        #pragma unroll
        for (int t = tstart - WARM; t < tstart; ++t) {
            const v2f xt = x[(size_t)t * N2 + col];
            (void)izi_step(xt.x, vx, rx);
            (void)izi_step(xt.y, vy, ry);
        }
    }

    u32 bits0 = 0u, bits1 = 0u;

    // Ping-pong register pipeline (round-2 structure, proven absmax 0.0).
    v2f buf[2][NP];
    #pragma unroll
    for (int i = 0; i < NP; ++i)
        buf[0][i] = x[(size_t)(tstart + i) * N2 + col];

    #pragma unroll
    for (int tb = 0; tb < NBLK; ++tb) {
        const int cur = tb & 1;
        const int nxt = cur ^ 1;
        const int t0 = tstart + tb * NP;

        if (tb < NBLK - 1) {
            #pragma unroll
            for (int i = 0; i < NP; ++i)
                buf[nxt][i] = x[(size_t)(t0 + NP + i) * N2 + col];
        }
        __builtin_amdgcn_sched_barrier(0);

        #pragma unroll
        for (int i = 0; i < NP; ++i) {
            const int k = tb * NP + i;      // bit index within chunk, 0..31
            const v2f xt = buf[cur][i];
            if (izi_step(xt.x, vx, rx)) bits0 |= (1u << k);
            if (izi_step(xt.y, vy, ry)) bits1 |= (1u << k);
        }
    }

    // Stash the packed word pair at row tstart of the OUTPUT buffer
    // (bitcast). k2's expander thread for (c, col) reads exactly this
    // location before overwriting it. Plain (cached) store: 4 MB total,
    // stays L2/L3-hot for k2.
    v2u w; w.x = bits0; w.y = bits1;
    outp[(size_t)tstart * N2 + col] = w;
}

// ---------------- k2: bit-expand (write-dominated, fill-shaped) --------

__global__ __launch_bounds__(1024, 2) void izi_expand(float* __restrict__ out) {
    const int col = blockIdx.x * 1024 + threadIdx.x;  // float2 column
    const int c = blockIdx.y;                         // time chunk 0..15
    const int tstart = c * TCH;

    // Read own packed word (written by k1; only this thread ever touches
    // row tstart at this column before the i=0 store below).
    const v2u w = ((const v2u*)out)[(size_t)tstart * N2 + col];

    v2f* o2 = (v2f*)out;
    #pragma unroll
    for (int i = 0; i < TCH; ++i) {
        v2f o;
        o.x = (w.x >> i) & 1u ? 1.0f : 0.0f;
        o.y = (w.y >> i) & 1u ? 1.0f : 0.0f;
        __builtin_nontemporal_store(o, o2 + (size_t)(tstart + i) * N2 + col);
    }
}

extern "C" void kernel_launch(void* const* d_in, const int* in_sizes, int n_in,
                              void* d_out, int out_size, void* d_ws, size_t ws_size,
                              hipStream_t stream) {
    const v2f* x = (const v2f*)d_in[0];
    // k1: 128 x-blocks x 16 chunks = 2048 blocks (8/CU, 32 waves/CU).
    izi_pack<<<dim3(N2 / 256, NCHUNK), dim3(256), 0, stream>>>(x, (v2u*)d_out);
    // k2: 32 x-blocks x 16 chunks = 512 blocks of 1024 thr (2/CU, 32
    // waves/CU); 8 KB contiguous per row per block — fillBuffer-shaped.
    izi_expand<<<dim3(N2 / 1024, NCHUNK), dim3(1024), 0, stream>>>((float*)d_out);
}

// Round 8
// 242.387 us; speedup vs baseline: 1.0052x; 1.0052x over previous
//
#include <hip/hip_runtime.h>

// Izhikevich spiking neuron scan — L3-prewarm + proven register-pipeline scan.
// (Round-8 = round-7 resubmitted verbatim: the round-7 bench died to a
// container-acquisition failure, not a kernel problem; theory untested.)
//
// x: [T=512, N=65536] f32. out: [T, N] f32 spike train (0.0 / 1.0).
//
// Round-7 theory: six structurally different kernels (reg-pipeline, LDS-DMA
// deep pipelines, pure-read bitpack split) ALL cap at 2.5-2.9 TB/s. R6
// isolated it to the READ pattern: each block reads 2-4 KB islands strided
// 256 KB; with ~256 B channel interleave an island gives <=1 unit per
// pseudo-channel => every access opens a fresh DRAM row (~40% efficiency),
// while contiguous sweeps (copy 6.3, fillBuffer 6.6 TB/s) stream within
// rows. Aggregate coverage doesn't save it: chunk-mates decohere
// temporally. No island size a block can own fixes per-channel run length.
//
// Fix: x (128 MB) FITS in the 256 MB memory-side Infinity Cache. Kernel 1
// (prewarm) sweeps x contiguously — dense 8 MB moving band, DRAM-friendly,
// ~21 us — allocating every line in L3. Kernel 2 (the round-2 scan,
// verified absmax 0.0, best measured structure) then reads L3-hot: its
// scattered pattern hits MALL, not DRAM row buffers. Same-stream order
// serializes. Signature prediction: scan FETCH_SIZE collapses to <15 MB.
//
// Recurrence (bit-identical to all verified prior versions):
//   v = (4v^2 + 5v + 1.4 - r + x_t) * DT   (DT = 1/512)
//   r = 0.02 * (0.2v - v) * DT             (uses NEW v)
//   fire = v >= 0.3 ; fire -> v = -0.065, r += 0.008 ; out_t = fire
//
// Time-split justification (verified absmax=0 six times): the map contracts
// prior state by ~(5/512)/step; 8 warmup steps shrink any init-state error
// below fp32 ulp.

#define T_STEPS 512
#define N_NEUR  65536
#define N2      (N_NEUR / 2)     // 32768 float2 columns
#define N4      (N_NEUR / 4)     // 16384 float4 columns
#define DT      (1.0f / 512.0f)
#define TCH     32               // timesteps per chunk (512/16)
#define WARM    8                // warmup steps to converge state at chunk start
#define NP      8                // prefetch batch depth (timesteps per tile)
#define NBLK    (TCH / NP)       // 4 tiles per chunk

typedef float v2f __attribute__((ext_vector_type(2)));
typedef float v4f __attribute__((ext_vector_type(4)));

// ---------------- k0: contiguous L3 prewarm (pure read sweep) ----------

__global__ __launch_bounds__(256, 8) void prewarm(const v4f* __restrict__ x) {
    // 2048 blocks x 256 threads; grid-stride over 8,388,608 float4s in 16
    // steps. Instantaneous window = 2048 x 4 KB = 8 MB dense band sweeping
    // the 128 MB array: long per-channel DRAM-row runs, copy-shaped.
    const int stride = 2048 * 256;
    int idx = blockIdx.x * 256 + threadIdx.x;
    v4f acc = {0.0f, 0.0f, 0.0f, 0.0f};
    #pragma unroll 4
    for (int i = 0; i < 16; ++i) {
        acc += x[idx];
        idx += stride;
    }
    // Keep the loads live without any store (rule #17: skip-DCE guard).
    asm volatile("" :: "v"(acc.x), "v"(acc.y), "v"(acc.z), "v"(acc.w));
}

// ---------------- k1: round-2 scan (verified, best structure) ----------

__device__ __forceinline__ float izi_step(float xt, float& v, float& r) {
    v = (4.0f * v * v + 5.0f * v + 1.4f - r + xt) * DT;
    r = 0.02f * (0.2f * v - v) * DT;
    const bool fire = v >= 0.3f;
    if (fire) { v = -0.065f; r += 0.008f; }
    return fire ? 1.0f : 0.0f;
}

__device__ __forceinline__ v2f izi_step2(const v2f xt, v2f& v, v2f& r) {
    v2f o;
    float vx = v.x, rx = r.x, vy = v.y, ry = r.y;
    o.x = izi_step(xt.x, vx, rx);
    o.y = izi_step(xt.y, vy, ry);
    v.x = vx; r.x = rx; v.y = vy; r.y = ry;
    return o;
}

__global__ __launch_bounds__(256, 4) void izi_kernel(const v2f* __restrict__ x,
                                                     v2f* __restrict__ out) {
    const int col = blockIdx.x * 256 + threadIdx.x;  // float2 column, coalesced
    const int c = blockIdx.y;                        // time chunk 0..15
    const int tstart = c * TCH;

    v2f v; v.x = -0.065f; v.y = -0.065f;
    v2f r; r.x = 0.0f;    r.y = 0.0f;

    if (c > 0) {
        #pragma unroll
        for (int t = tstart - WARM; t < tstart; ++t) {
            const v2f xt = x[(size_t)t * N2 + col];
            (void)izi_step2(xt, v, r);
        }
    }

    // Ping-pong pipeline: buf[2][NP], fully unrolled, static indices.
    v2f buf[2][NP];
    #pragma unroll
    for (int i = 0; i < NP; ++i)
        buf[0][i] = x[(size_t)(tstart + i) * N2 + col];

    #pragma unroll
    for (int tb = 0; tb < NBLK; ++tb) {
        const int cur = tb & 1;
        const int nxt = cur ^ 1;
        const int t0 = tstart + tb * NP;

        if (tb < NBLK - 1) {
            // Batch-issue next tile's 8 loads before touching this tile.
            #pragma unroll
            for (int i = 0; i < NP; ++i)
                buf[nxt][i] = x[(size_t)(t0 + NP + i) * N2 + col];
        }
        // Pin: loads above stay above the compute below.
        __builtin_amdgcn_sched_barrier(0);

        #pragma unroll
        for (int i = 0; i < NP; ++i) {
            const v2f o = izi_step2(buf[cur][i], v, r);
            __builtin_nontemporal_store(o, &out[(size_t)(t0 + i) * N2 + col]);
        }
    }
}

extern "C" void kernel_launch(void* const* d_in, const int* in_sizes, int n_in,
                              void* d_out, int out_size, void* d_ws, size_t ws_size,
                              hipStream_t stream) {
    const v4f* x4 = (const v4f*)d_in[0];
    const v2f* x = (const v2f*)d_in[0];
    v2f* out = (v2f*)d_out;
    // k0: contiguous sweep loads all of x into the 256 MB Infinity Cache.
    prewarm<<<dim3(2048), dim3(256), 0, stream>>>(x4);
    // k1: 128 neuron-blocks x 16 time-chunks = 2048 blocks (8/CU, 32
    // waves/CU), reads now L3-hot.
    izi_kernel<<<dim3(N2 / 256, T_STEPS / TCH), dim3(256), 0, stream>>>(x, out);
}